// Round 13
// baseline (132.140 us; speedup 1.0000x reference)
//
#include <hip/hip_runtime.h>
#include <math.h>

// Problem constants (fixed by setup_inputs)
constexpr int Bb = 4, Hc = 64, Wc = 64, Cc = 256, Cf = 128, E = 64, KK = 25, F = 256;
constexpr int Hf = 128, Wf = 128;
constexpr int Nc = Bb * Hc * Wc;   // 16384 coarse pixels
constexpr int Nf = Bb * Hf * Wf;   // 65536 fine pixels

typedef __attribute__((ext_vector_type(8))) short bf16x8;
typedef __attribute__((ext_vector_type(4))) float f32x4;

__device__ inline unsigned short f2b(float f) {
  union { float f; unsigned u; } v; v.f = f;
  return (unsigned short)((v.u + 0x7FFF + ((v.u >> 16) & 1)) >> 16);
}

// ---------------------------------------------------------------------------
// prep: 0..15 Wt1 transpose; 16..18 sprep; 19..34 W12 (self-contained);
//       35 b12; 36..291 gate (fat pipelined GEMV blocks)
__global__ __launch_bounds__(256) void prep_kernel(
    const float* __restrict__ W1, const float* __restrict__ W2,
    unsigned short* __restrict__ Wt1, unsigned short* __restrict__ Wt12,
    float* __restrict__ b12f, const float* __restrict__ b1,
    const float* __restrict__ b2,
    const float* __restrict__ fw, const float* __restrict__ cw,
    const float* __restrict__ cntw, unsigned short* __restrict__ Wtf,
    unsigned short* __restrict__ Wtc, unsigned short* __restrict__ Wtcnt,
    const float* __restrict__ coarse, const float* __restrict__ gw,
    const float* __restrict__ gb, float* __restrict__ gatec) {
  __shared__ __align__(16) char smem[64 * 72 * 2 * 2];  // 18432 B shared pool
  int idx = blockIdx.x, t = threadIdx.x;

  if (idx < 16) {
    float (*tile)[65] = (float(*)[65])smem;
    int k0 = ((idx >> 2) & 3) * 64, n0 = (idx & 3) * 64;
    int r0 = t >> 6, c = t & 63;
    for (int r = r0; r < 64; r += 4)
      tile[r][c] = W1[(size_t)(k0 + r) * 256 + n0 + c];
    __syncthreads();
    for (int r = r0; r < 64; r += 4)
      Wt1[(size_t)(n0 + r) * 256 + k0 + c] = f2b(tile[c][r]);
  } else if (idx < 19) {
    int sec = idx - 16;
    if (sec == 0) {
      for (int i = t; i < 64 * 128; i += 256) {
        int n = i & 63, k = i >> 6;
        Wtf[n * 128 + k] = f2b(fw[k * 64 + n]);
      }
    } else if (sec == 1) {
      for (int i = t; i < 64 * 256; i += 256) {
        int n = i & 63, k = i >> 6;
        Wtc[n * 256 + k] = f2b(cw[k * 64 + n]);
      }
    } else {
      for (int i = t; i < 32 * 576; i += 256) {
        int n = i & 31, kk = i >> 5;
        Wtcnt[n * 576 + kk] = (n < 25) ? f2b(cntw[kk * 25 + n]) : (unsigned short)0;
      }
    }
  } else if (idx < 35) {
    unsigned short* a_s = (unsigned short*)smem;
    unsigned short* b_s = (unsigned short*)smem + 64 * 72;
    int sub = idx - 19;
    int nbase = (sub & 3) * 64, k0 = (sub >> 2) * 64;
    int wid = t >> 6, lane = t & 63;
    int lr = lane & 15, lg = lane >> 4;
    const f32x4 zero4 = {0.f, 0.f, 0.f, 0.f};
    f32x4 acc[4] = {zero4, zero4, zero4, zero4};

    for (int mc = 0; mc < 4; mc++) {
      for (int i = t; i < 64 * 16; i += 256) {
        int r = i >> 4, c4 = i & 15;
        float4 v = *(const float4*)&W1[(size_t)(k0 + r) * 256 + mc * 64 + c4 * 4];
        *(short4*)&a_s[r * 72 + c4 * 4] =
            make_short4((short)f2b(v.x), (short)f2b(v.y), (short)f2b(v.z), (short)f2b(v.w));
      }
      for (int i = t; i < 64 * 16; i += 256) {
        int m = i >> 4, n4 = i & 15;
        float4 v = *(const float4*)&W2[(size_t)(mc * 64 + m) * 256 + nbase + n4 * 4];
        b_s[(n4 * 4 + 0) * 72 + m] = f2b(v.x);
        b_s[(n4 * 4 + 1) * 72 + m] = f2b(v.y);
        b_s[(n4 * 4 + 2) * 72 + m] = f2b(v.z);
        b_s[(n4 * 4 + 3) * 72 + m] = f2b(v.w);
      }
      __syncthreads();
      #pragma unroll
      for (int kt = 0; kt < 2; kt++) {
        bf16x8 a = *(const bf16x8*)&a_s[(wid * 16 + lr) * 72 + kt * 32 + lg * 8];
        #pragma unroll
        for (int nt = 0; nt < 4; nt++) {
          bf16x8 bb = *(const bf16x8*)&b_s[(nt * 16 + lr) * 72 + kt * 32 + lg * 8];
          acc[nt] = __builtin_amdgcn_mfma_f32_16x16x32_bf16(a, bb, acc[nt], 0, 0, 0);
        }
      }
      __syncthreads();
    }
    #pragma unroll
    for (int nt = 0; nt < 4; nt++)
      #pragma unroll
      for (int r = 0; r < 4; r++)
        Wt12[(size_t)(nbase + nt * 16 + lr) * 256 + k0 + wid * 16 + lg * 4 + r] =
            f2b(acc[nt][r]);
  } else if (idx == 35) {
    int n = t;
    float acc = b2[n];
    #pragma unroll 8
    for (int m = 0; m < 256; m++) acc += b1[m] * W2[(size_t)m * 256 + n];
    b12f[n] = acc;
  } else {
    // ---- gate GEMV: 256 blocks; each wave: 16 px = 2 rounds x 8 in flight ----
    int w = t >> 6, lane = t & 63;
    int base = (idx - 36) * 64 + w * 16;
    const float4 wv = *(const float4*)(gw + lane * 4);
    float gb0 = gb[0];
    #pragma unroll
    for (int rnd = 0; rnd < 2; rnd++) {
      int p0 = base + rnd * 8;
      float a0, a1, a2, a3, a4, a5, a6, a7;
      {
        float4 v0 = *(const float4*)(coarse + (size_t)(p0 + 0) * 256 + lane * 4);
        float4 v1 = *(const float4*)(coarse + (size_t)(p0 + 1) * 256 + lane * 4);
        float4 v2 = *(const float4*)(coarse + (size_t)(p0 + 2) * 256 + lane * 4);
        float4 v3 = *(const float4*)(coarse + (size_t)(p0 + 3) * 256 + lane * 4);
        float4 v4 = *(const float4*)(coarse + (size_t)(p0 + 4) * 256 + lane * 4);
        float4 v5 = *(const float4*)(coarse + (size_t)(p0 + 5) * 256 + lane * 4);
        float4 v6 = *(const float4*)(coarse + (size_t)(p0 + 6) * 256 + lane * 4);
        float4 v7 = *(const float4*)(coarse + (size_t)(p0 + 7) * 256 + lane * 4);
        a0 = v0.x * wv.x + v0.y * wv.y + v0.z * wv.z + v0.w * wv.w;
        a1 = v1.x * wv.x + v1.y * wv.y + v1.z * wv.z + v1.w * wv.w;
        a2 = v2.x * wv.x + v2.y * wv.y + v2.z * wv.z + v2.w * wv.w;
        a3 = v3.x * wv.x + v3.y * wv.y + v3.z * wv.z + v3.w * wv.w;
        a4 = v4.x * wv.x + v4.y * wv.y + v4.z * wv.z + v4.w * wv.w;
        a5 = v5.x * wv.x + v5.y * wv.y + v5.z * wv.z + v5.w * wv.w;
        a6 = v6.x * wv.x + v6.y * wv.y + v6.z * wv.z + v6.w * wv.w;
        a7 = v7.x * wv.x + v7.y * wv.y + v7.z * wv.z + v7.w * wv.w;
      }
      #pragma unroll
      for (int off2 = 32; off2; off2 >>= 1) {
        a0 += __shfl_xor(a0, off2);
        a1 += __shfl_xor(a1, off2);
        a2 += __shfl_xor(a2, off2);
        a3 += __shfl_xor(a3, off2);
        a4 += __shfl_xor(a4, off2);
        a5 += __shfl_xor(a5, off2);
        a6 += __shfl_xor(a6, off2);
        a7 += __shfl_xor(a7, off2);
      }
      if (lane == 0) {
        gatec[p0 + 0] = 1.f / (1.f + expf(-(a0 + gb0)));
        gatec[p0 + 1] = 1.f / (1.f + expf(-(a1 + gb0)));
        gatec[p0 + 2] = 1.f / (1.f + expf(-(a2 + gb0)));
        gatec[p0 + 3] = 1.f / (1.f + expf(-(a3 + gb0)));
        gatec[p0 + 4] = 1.f / (1.f + expf(-(a4 + gb0)));
        gatec[p0 + 5] = 1.f / (1.f + expf(-(a5 + gb0)));
        gatec[p0 + 6] = 1.f / (1.f + expf(-(a6 + gb0)));
        gatec[p0 + 7] = 1.f / (1.f + expf(-(a7 + gb0)));
      }
    }
  }
}

// ---------------------------------------------------------------------------
// emb (both resolutions): out_bf16[px][64] = in[px][K] @ Wt[64][K]
template <int K>
__device__ inline void emb_body(const float* __restrict__ in,
                                const unsigned short* __restrict__ Wt,
                                const float* __restrict__ bias,
                                unsigned short* __restrict__ out, int pxb,
                                unsigned short* a_s) {
  constexpr int LDA = K + 8;
  int t = threadIdx.x;
  constexpr int KC = K / 4;
  for (int idx = t; idx < 64 * KC; idx += 256) {
    int px = idx / KC, kc = idx % KC;
    float4 v = *(const float4*)&in[(size_t)(pxb + px) * K + kc * 4];
    *(short4*)&a_s[px * LDA + kc * 4] =
        make_short4((short)f2b(v.x), (short)f2b(v.y), (short)f2b(v.z), (short)f2b(v.w));
  }
  __syncthreads();

  int wid = t >> 6, lane = t & 63;
  int lr = lane & 15, lg = lane >> 4;
  const f32x4 zero4 = {0.f, 0.f, 0.f, 0.f};
  f32x4 acc[4] = {zero4, zero4, zero4, zero4};

  #pragma unroll
  for (int kt = 0; kt < K / 32; kt++) {
    bf16x8 a = *(const bf16x8*)&a_s[(wid * 16 + lr) * LDA + kt * 32 + lg * 8];
    #pragma unroll
    for (int nt = 0; nt < 4; nt++) {
      bf16x8 bb = *(const bf16x8*)&Wt[(size_t)(nt * 16 + lr) * K + kt * 32 + lg * 8];
      acc[nt] = __builtin_amdgcn_mfma_f32_16x16x32_bf16(a, bb, acc[nt], 0, 0, 0);
    }
  }

  #pragma unroll
  for (int nt = 0; nt < 4; nt++) {
    int n = nt * 16 + lr;
    float bv = bias ? bias[n] : 0.f;
    #pragma unroll
    for (int r = 0; r < 4; r++) {
      int px = wid * 16 + lg * 4 + r;
      out[(size_t)(pxb + px) * 64 + n] = f2b(acc[nt][r] + bv);
    }
  }
}

__global__ __launch_bounds__(256) void emb_both_kernel(
    const float* __restrict__ fine, const unsigned short* __restrict__ Wtf,
    const float* __restrict__ fbias, unsigned short* __restrict__ femb,
    const float* __restrict__ coarse, const unsigned short* __restrict__ Wtc,
    unsigned short* __restrict__ cemb) {
  __shared__ __align__(16) unsigned short a_s[64 * 264];
  int idx = blockIdx.x;
  if (idx < Nf / 64) emb_body<128>(fine, Wtf, fbias, femb, idx * 64, a_s);
  else               emb_body<256>(coarse, Wtc, nullptr, cemb, (idx - Nf / 64) * 64, a_s);
}

// ---------------------------------------------------------------------------
// content v2: 16x16 output tile / block; B-frags preloaded in registers
// (18 per nt-phase), reused across 4 M-tiles -> 8 MFMA per B-load.
__global__ __launch_bounds__(256) void content_both_kernel(
    const unsigned short* __restrict__ femb, const unsigned short* __restrict__ cemb,
    const unsigned short* __restrict__ Wtcnt, const float* __restrict__ cb,
    float* __restrict__ kff, float* __restrict__ kfc) {
  __shared__ __align__(16) unsigned short a_s[324 * 72];  // 46656 B (18x18 halo)
  int idx = blockIdx.x, t = threadIdx.x;
  const unsigned short* emb;
  float* out;
  int b, i0, j0, Hd, Wd;
  if (idx < 256) {
    b = idx >> 6; int rem = idx & 63;
    i0 = (rem >> 3) * 16; j0 = (rem & 7) * 16; Hd = 128; Wd = 128;
    emb = femb; out = kff;
  } else {
    int i2 = idx - 256;
    b = i2 >> 4; int rem = i2 & 15;
    i0 = (rem >> 2) * 16; j0 = (rem & 3) * 16; Hd = 64; Wd = 64;
    emb = cemb; out = kfc;
  }

  // stage 18x18 halo x 64 ch (bf16, 8B chunks)
  for (int i = t; i < 324 * 16; i += 256) {
    int cell = i >> 4, ck = i & 15;
    int gi = i0 - 1 + cell / 18;
    int gj = j0 - 1 + cell % 18;
    short4 v = make_short4(0, 0, 0, 0);
    if (gi >= 0 && gi < Hd && gj >= 0 && gj < Wd)
      v = *(const short4*)&emb[(size_t)((b * Hd + gi) * Wd + gj) * 64 + ck * 4];
    *(short4*)&a_s[cell * 72 + ck * 4] = v;
  }
  __syncthreads();

  int wid = t >> 6, lane = t & 63;
  int lr = lane & 15, lg = lane >> 4;
  const f32x4 zero4 = {0.f, 0.f, 0.f, 0.f};
  f32x4 acc[4][2];
  #pragma unroll
  for (int mt = 0; mt < 4; mt++)
    #pragma unroll
    for (int nt = 0; nt < 2; nt++) acc[mt][nt] = zero4;

  // nt-phased: preload 18 B-frags (tap x kt) into regs, sweep 4 M-tiles
  #pragma unroll
  for (int nt = 0; nt < 2; nt++) {
    bf16x8 wb[9][2];
    #pragma unroll
    for (int tap = 0; tap < 9; tap++)
      #pragma unroll
      for (int kt = 0; kt < 2; kt++)
        wb[tap][kt] = *(const bf16x8*)&Wtcnt[(size_t)(nt * 16 + lr) * 576 + tap * 64 + kt * 32 + lg * 8];

    #pragma unroll
    for (int mt = 0; mt < 4; mt++) {
      int m = wid * 4 + mt;             // output row (pi) of the 16x16 tile
      #pragma unroll
      for (int di = 0; di < 3; di++) {
        #pragma unroll
        for (int dj = 0; dj < 3; dj++) {
          int cell = (m + di) * 18 + (lr + dj);
          int tap = di * 3 + dj;
          #pragma unroll
          for (int kt = 0; kt < 2; kt++) {
            bf16x8 a = *(const bf16x8*)&a_s[cell * 72 + kt * 32 + lg * 8];
            acc[mt][nt] = __builtin_amdgcn_mfma_f32_16x16x32_bf16(a, wb[tap][kt], acc[mt][nt], 0, 0, 0);
          }
        }
      }
    }
  }

  // store: output px = (pi = m, pj = lg*4+r), ch = nt*16+lr
  #pragma unroll
  for (int mt = 0; mt < 4; mt++) {
    int m = wid * 4 + mt;
    int gi = i0 + m;
    #pragma unroll
    for (int nt = 0; nt < 2; nt++) {
      int ch = nt * 16 + lr;
      if (ch < 25) {
        float bv = cb[ch];
        #pragma unroll
        for (int r = 0; r < 4; r++) {
          int gj = j0 + lg * 4 + r;
          out[(size_t)((b * Hd + gi) * Wd + gj) * 25 + ch] = acc[mt][nt][r] + bv;
        }
      }
    }
  }
}

// ---------------------------------------------------------------------------
// carafe (64 px / block): 8x8 fine tile -> 8x8 coarse window. cu_g bf16.
__global__ __launch_bounds__(256) void carafe_kernel(
    const float* __restrict__ coarse, const float* __restrict__ kff,
    const float* __restrict__ kfc, unsigned short* __restrict__ cu_g) {
  __shared__ __align__(16) unsigned short buf[256 * 72];   // win_t, then cu_s
  __shared__ __align__(16) unsigned short m_ext[64 * 72];  // 9216 B
  unsigned short* win_t = buf;
  unsigned short* cu_s  = buf;

  int t = threadIdx.x;
  int b = blockIdx.z;
  int i0 = blockIdx.y * 8, j0 = blockIdx.x * 8;
  int hw0 = (i0 >> 1) - 2, ww0 = (j0 >> 1) - 2;

  {
    #pragma unroll
    for (int p0 = 0; p0 < 64; p0 += 4) {
      unsigned short vals[4];
      #pragma unroll
      for (int q = 0; q < 4; q++) {
        int p = p0 + q;
        int h = hw0 + (p >> 3), w = ww0 + (p & 7);
        float v = 0.f;
        if (h >= 0 && h < 64 && w >= 0 && w < 64)
          v = coarse[(size_t)((b * 64 + h) * 64 + w) * 256 + t];
        vals[q] = f2b(v);
      }
      *(short4*)&win_t[t * 72 + p0] =
          make_short4((short)vals[0], (short)vals[1], (short)vals[2], (short)vals[3]);
    }
  }
  if (t < 64) {
    int ti = t >> 3, tj = t & 7;
    int i = i0 + ti, j = j0 + tj;
    size_t fpx = (size_t)((b * 128 + i) * 128 + j);
    size_t cpx = (size_t)((b * 64 + (i >> 1)) * 64 + (j >> 1));
    float v[25];
    float mx = -1e30f;
    #pragma unroll
    for (int m = 0; m < 25; m++) {
      v[m] = kff[fpx * 25 + m] + kfc[cpx * 25 + m];
      mx = fmaxf(mx, v[m]);
    }
    float s = 0.f;
    #pragma unroll
    for (int m = 0; m < 25; m++) { v[m] = expf(v[m] - mx); s += v[m]; }
    float inv = 1.f / s;
    unsigned* row32 = (unsigned*)&m_ext[t * 72];
    #pragma unroll
    for (int q = 0; q < 36; q++) row32[q] = 0;
    int wib = ti >> 1, wjb = tj >> 1;
    #pragma unroll
    for (int di = 0; di < 5; di++)
      #pragma unroll
      for (int dj = 0; dj < 5; dj++)
        m_ext[t * 72 + (wib + di) * 8 + (wjb + dj)] = f2b(v[di * 5 + dj] * inv);
  }
  __syncthreads();

  int wid = t >> 6, lane = t & 63;
  int lr = lane & 15, lg = lane >> 4;
  const f32x4 zero4 = {0.f, 0.f, 0.f, 0.f};

  f32x4 acc0[4][4];
  #pragma unroll
  for (int mi = 0; mi < 4; mi++)
    #pragma unroll
    for (int ni = 0; ni < 4; ni++) acc0[mi][ni] = zero4;
  #pragma unroll
  for (int kt = 0; kt < 2; kt++) {
    bf16x8 am[4];
    #pragma unroll
    for (int mi = 0; mi < 4; mi++)
      am[mi] = *(const bf16x8*)&m_ext[(mi * 16 + lr) * 72 + kt * 32 + lg * 8];
    #pragma unroll
    for (int ni = 0; ni < 4; ni++) {
      bf16x8 bb = *(const bf16x8*)&win_t[(size_t)(wid * 64 + ni * 16 + lr) * 72 + kt * 32 + lg * 8];
      #pragma unroll
      for (int mi = 0; mi < 4; mi++)
        acc0[mi][ni] = __builtin_amdgcn_mfma_f32_16x16x32_bf16(am[mi], bb, acc0[mi][ni], 0, 0, 0);
    }
  }
  __syncthreads();

  #pragma unroll
  for (int mi = 0; mi < 4; mi++)
    #pragma unroll
    for (int ni = 0; ni < 4; ni++)
      #pragma unroll
      for (int r = 0; r < 4; r++)
        cu_s[(mi * 16 + lg * 4 + r) * 264 + wid * 64 + ni * 16 + lr] = f2b(acc0[mi][ni][r]);
  __syncthreads();

  for (int c = t; c < 2048; c += 256) {
    int p = c >> 5, off = (c & 31) << 3;
    int gi = i0 + (p >> 3), gj = j0 + (p & 7);
    bf16x8 v = *(const bf16x8*)&cu_s[p * 264 + off];
    *(bf16x8*)&cu_g[(size_t)((b * 128 + gi) * 128 + gj) * 256 + off] = v;
  }
}

// ---------------------------------------------------------------------------
// proj: persistent 4-tile pipeline, weights in regs, LDS double buffer.
__global__ __launch_bounds__(256, 2) void proj_kernel(
    const unsigned short* __restrict__ cu_g, const float* __restrict__ gatec,
    const unsigned short* __restrict__ Wt1, const float* __restrict__ b1,
    const unsigned short* __restrict__ Wt12, const float* __restrict__ b12,
    float* __restrict__ out) {
  __shared__ __align__(16) unsigned short a_s[2][64 * 264];
  __shared__ float g_s[2][32];
  int t = threadIdx.x;
  int bid = blockIdx.x;
  int cg = bid >> 8;
  int g  = bid & 255;
  int wid = t >> 6, lane = t & 63;
  int lr = lane & 15, lg = lane >> 4;
  int n0 = cg * 64 + wid * 16;

  bf16x8 wb1[8], wb12[8];
  #pragma unroll
  for (int kt = 0; kt < 8; kt++) {
    size_t wrow = (size_t)(n0 + lr) * 256 + kt * 32 + lg * 8;
    wb1[kt]  = *(const bf16x8*)&Wt1[wrow];
    wb12[kt] = *(const bf16x8*)&Wt12[wrow];
  }
  float b1v  = b1[n0 + lr];
  float b12v = b12[n0 + lr];

  {
    size_t m0 = (size_t)g * 256;
    for (int c = t; c < 2048; c += 256) {
      int row = c >> 5, off = (c & 31) << 3;
      *(bf16x8*)&a_s[0][row * 264 + off] = *(const bf16x8*)&cu_g[(m0 + row) * 256 + off];
    }
    if (t < 32) {
      int b_ = (int)(m0 >> 14), ii = (int)((m0 >> 7) & 127), j0 = (int)(m0 & 127);
      g_s[0][t] = gatec[(size_t)(b_ * 64 + (ii >> 1)) * 64 + (j0 >> 1) + t];
    }
  }
  __syncthreads();

  const f32x4 zero4 = {0.f, 0.f, 0.f, 0.f};

  for (int it = 0; it < 4; ++it) {
    int cur = it & 1, nxt = cur ^ 1;
    size_t m0i = (size_t)(g * 4 + it) * 64;

    bf16x8 pf[8];
    float gpf = 0.f;
    if (it < 3) {
      size_t m0n = m0i + 64;
      #pragma unroll
      for (int q = 0; q < 8; q++) {
        int c = t + q * 256;
        int row = c >> 5, off = (c & 31) << 3;
        pf[q] = *(const bf16x8*)&cu_g[(m0n + row) * 256 + off];
      }
      if (t < 32) {
        int b_ = (int)(m0n >> 14), ii = (int)((m0n >> 7) & 127), j0 = (int)(m0n & 127);
        gpf = gatec[(size_t)(b_ * 64 + (ii >> 1)) * 64 + (j0 >> 1) + t];
      }
    }

    f32x4 accc[4] = {zero4, zero4, zero4, zero4};
    f32x4 accf[4] = {zero4, zero4, zero4, zero4};
    #pragma unroll
    for (int kt = 0; kt < 8; kt++) {
      #pragma unroll
      for (int mi = 0; mi < 4; mi++) {
        bf16x8 a = *(const bf16x8*)&a_s[cur][(mi * 16 + lr) * 264 + kt * 32 + lg * 8];
        accc[mi] = __builtin_amdgcn_mfma_f32_16x16x32_bf16(a, wb1[kt],  accc[mi], 0, 0, 0);
        accf[mi] = __builtin_amdgcn_mfma_f32_16x16x32_bf16(a, wb12[kt], accf[mi], 0, 0, 0);
      }
    }

    if (it < 3) {
      #pragma unroll
      for (int q = 0; q < 8; q++) {
        int c = t + q * 256;
        int row = c >> 5, off = (c & 31) << 3;
        *(bf16x8*)&a_s[nxt][row * 264 + off] = pf[q];
      }
      if (t < 32) g_s[nxt][t] = gpf;
    }

    #pragma unroll
    for (int mi = 0; mi < 4; mi++) {
      #pragma unroll
      for (int r = 0; r < 4; r++) {
        int row = mi * 16 + lg * 4 + r;
        float gg = g_s[cur][row >> 1];
        float f_out = accf[mi][r] + b12v;
        float c_out = accc[mi][r] + b1v;
        out[(m0i + row) * 256 + n0 + lr] = gg * f_out + (1.f - gg) * c_out;
      }
    }

    if (it < 3) __syncthreads();
  }
}

// ---------------------------------------------------------------------------
extern "C" void kernel_launch(void* const* d_in, const int* in_sizes, int n_in,
                              void* d_out, int out_size, void* d_ws, size_t ws_size,
                              hipStream_t stream) {
  const float* fine        = (const float*)d_in[0];
  const float* coarse      = (const float*)d_in[1];
  const float* gate_w      = (const float*)d_in[2];
  const float* gate_b      = (const float*)d_in[3];
  const float* ss_fine_w   = (const float*)d_in[4];
  const float* ss_fine_b   = (const float*)d_in[5];
  const float* ss_coarse_w = (const float*)d_in[6];
  const float* ss_content_w= (const float*)d_in[7];
  const float* ss_content_b= (const float*)d_in[8];
  const float* W1          = (const float*)d_in[9];
  const float* b1          = (const float*)d_in[10];
  const float* W2          = (const float*)d_in[11];
  const float* b2          = (const float*)d_in[12];
  float* out = (float*)d_out;

  char* ws = (char*)d_ws;
  size_t off = 0;
  float* gatec = (float*)(ws + off); off += 131072;
  unsigned short* femb = (unsigned short*)(ws + off); off += (size_t)Nf * 64 * 2;
  unsigned short* cemb = (unsigned short*)(ws + off); off += (size_t)Nc * 64 * 2;
  float* kff   = (float*)(ws + off); off += (size_t)Nf * 25 * 4;
  float* kfc   = (float*)(ws + off); off += (size_t)Nc * 25 * 4;
  unsigned short* Wt1 = (unsigned short*)(ws + off); off += 65536 * 2;
  unsigned short* Wtf = (unsigned short*)(ws + off); off += 64 * 128 * 2;
  unsigned short* Wtc = (unsigned short*)(ws + off); off += 64 * 256 * 2;
  unsigned short* Wtcnt = (unsigned short*)(ws + off); off += 32 * 576 * 2;
  unsigned short* Wt12 = (unsigned short*)(ws + off); off += 65536 * 2;
  float* b12f = (float*)(ws + off); off += 1024;
  unsigned short* cu_g = (unsigned short*)(ws + off); off += (size_t)Nf * 256 * 2;

  prep_kernel<<<36 + 256, 256, 0, stream>>>(
      W1, W2, Wt1, Wt12, b12f, b1, b2, ss_fine_w, ss_coarse_w, ss_content_w,
      Wtf, Wtc, Wtcnt, coarse, gate_w, gate_b, gatec);
  emb_both_kernel<<<Nf / 64 + Nc / 64, 256, 0, stream>>>(
      fine, Wtf, ss_fine_b, femb, coarse, Wtc, cemb);
  content_both_kernel<<<256 + 64, 256, 0, stream>>>(
      femb, cemb, Wtcnt, ss_content_b, kff, kfc);
  carafe_kernel<<<dim3(Wf / 8, Hf / 8, Bb), 256, 0, stream>>>(coarse, kff, kfc, cu_g);
  proj_kernel<<<1024, 256, 0, stream>>>(cu_g, gatec, Wt1, b1, Wt12, b12f, out);
}

// Round 14
// 114.077 us; speedup vs baseline: 1.1583x; 1.1583x over previous
//
#include <hip/hip_runtime.h>
#include <math.h>

// Problem constants (fixed by setup_inputs)
constexpr int Bb = 4, Hc = 64, Wc = 64, Cc = 256, Cf = 128, E = 64, KK = 25, F = 256;
constexpr int Hf = 128, Wf = 128;
constexpr int Nc = Bb * Hc * Wc;   // 16384 coarse pixels
constexpr int Nf = Bb * Hf * Wf;   // 65536 fine pixels

typedef __attribute__((ext_vector_type(8))) short bf16x8;
typedef __attribute__((ext_vector_type(4))) float f32x4;

__device__ inline unsigned short f2b(float f) {
  union { float f; unsigned u; } v; v.f = f;
  return (unsigned short)((v.u + 0x7FFF + ((v.u >> 16) & 1)) >> 16);
}

// ---------------------------------------------------------------------------
// prepA: small-weight transposes only (needed by emb/content). Flat map,
// 1 element/thread, 168 blocks -> all loads concurrently in flight.
__global__ __launch_bounds__(256) void prepA_kernel(
    const float* __restrict__ fw, const float* __restrict__ cw,
    const float* __restrict__ cntw, unsigned short* __restrict__ Wtf,
    unsigned short* __restrict__ Wtc, unsigned short* __restrict__ Wtcnt) {
  int gid = blockIdx.x * 256 + threadIdx.x;
  if (gid < 8192) {
    int i = gid;                      // fw is read contiguously
    int n = i & 63, k = i >> 6;
    Wtf[n * 128 + k] = f2b(fw[i]);
  } else if (gid < 8192 + 16384) {
    int i = gid - 8192;
    int n = i & 63, k = i >> 6;
    Wtc[n * 256 + k] = f2b(cw[i]);
  } else if (gid < 8192 + 16384 + 18432) {
    int i = gid - 8192 - 16384;
    int n = i & 31, kk = i >> 5;
    Wtcnt[n * 576 + kk] = (n < 25) ? f2b(cntw[kk * 25 + n]) : (unsigned short)0;
  }
}

// ---------------------------------------------------------------------------
// emb_both + prepB: blocks 0..1023 emb fine, 1024..1279 emb coarse,
// 1280..1295 Wt1 transpose, 1296..1311 W12 MFMA, 1312 b12, 1313..1568 gate.
// prepB outputs are consumed only by proj (2 launches later).
template <int K>
__device__ inline void emb_body(const float* __restrict__ in,
                                const unsigned short* __restrict__ Wt,
                                const float* __restrict__ bias,
                                unsigned short* __restrict__ out, int pxb,
                                unsigned short* a_s) {
  constexpr int LDA = K + 8;
  int t = threadIdx.x;
  constexpr int KC = K / 4;
  for (int idx = t; idx < 64 * KC; idx += 256) {
    int px = idx / KC, kc = idx % KC;
    float4 v = *(const float4*)&in[(size_t)(pxb + px) * K + kc * 4];
    *(short4*)&a_s[px * LDA + kc * 4] =
        make_short4((short)f2b(v.x), (short)f2b(v.y), (short)f2b(v.z), (short)f2b(v.w));
  }
  __syncthreads();

  int wid = t >> 6, lane = t & 63;
  int lr = lane & 15, lg = lane >> 4;
  const f32x4 zero4 = {0.f, 0.f, 0.f, 0.f};
  f32x4 acc[4] = {zero4, zero4, zero4, zero4};

  #pragma unroll
  for (int kt = 0; kt < K / 32; kt++) {
    bf16x8 a = *(const bf16x8*)&a_s[(wid * 16 + lr) * LDA + kt * 32 + lg * 8];
    #pragma unroll
    for (int nt = 0; nt < 4; nt++) {
      bf16x8 bb = *(const bf16x8*)&Wt[(size_t)(nt * 16 + lr) * K + kt * 32 + lg * 8];
      acc[nt] = __builtin_amdgcn_mfma_f32_16x16x32_bf16(a, bb, acc[nt], 0, 0, 0);
    }
  }

  #pragma unroll
  for (int nt = 0; nt < 4; nt++) {
    int n = nt * 16 + lr;
    float bv = bias ? bias[n] : 0.f;
    #pragma unroll
    for (int r = 0; r < 4; r++) {
      int px = wid * 16 + lg * 4 + r;
      out[(size_t)(pxb + px) * 64 + n] = f2b(acc[nt][r] + bv);
    }
  }
}

__global__ __launch_bounds__(256) void emb_prepB_kernel(
    const float* __restrict__ fine, const unsigned short* __restrict__ Wtf,
    const float* __restrict__ fbias, unsigned short* __restrict__ femb,
    const float* __restrict__ coarse, const unsigned short* __restrict__ Wtc,
    unsigned short* __restrict__ cemb,
    const float* __restrict__ W1, const float* __restrict__ W2,
    unsigned short* __restrict__ Wt1, unsigned short* __restrict__ Wt12,
    float* __restrict__ b12f, const float* __restrict__ b1,
    const float* __restrict__ b2, const float* __restrict__ gw,
    const float* __restrict__ gb, float* __restrict__ gatec) {
  __shared__ __align__(16) unsigned short pool[64 * 264];  // 33792 B shared pool
  int idx = blockIdx.x, t = threadIdx.x;

  if (idx < Nf / 64) {
    emb_body<128>(fine, Wtf, fbias, femb, idx * 64, pool);
  } else if (idx < 1280) {
    emb_body<256>(coarse, Wtc, nullptr, cemb, (idx - Nf / 64) * 64, pool);
  } else if (idx < 1296) {
    // ---- Wt1[n][k] = bf16(W1[k][n]) ----
    float (*tile)[65] = (float(*)[65])pool;  // 16640 B
    int sub = idx - 1280;
    int k0 = ((sub >> 2) & 3) * 64, n0 = (sub & 3) * 64;
    int r0 = t >> 6, c = t & 63;
    #pragma unroll
    for (int r = r0; r < 64; r += 4)
      tile[r][c] = W1[(size_t)(k0 + r) * 256 + n0 + c];
    __syncthreads();
    #pragma unroll
    for (int r = r0; r < 64; r += 4)
      Wt1[(size_t)(n0 + r) * 256 + k0 + c] = f2b(tile[c][r]);
  } else if (idx < 1312) {
    // ---- Wt12[n][k] = bf16((W1@W2)[k][n]) via MFMA, self-contained ----
    unsigned short* a_s = pool;            // [64*72]
    unsigned short* b_s = pool + 64 * 72;  // [64*72]
    int sub = idx - 1296;
    int nbase = (sub & 3) * 64, k0 = (sub >> 2) * 64;
    int wid = t >> 6, lane = t & 63;
    int lr = lane & 15, lg = lane >> 4;
    const f32x4 zero4 = {0.f, 0.f, 0.f, 0.f};
    f32x4 acc[4] = {zero4, zero4, zero4, zero4};

    for (int mc = 0; mc < 4; mc++) {
      for (int i = t; i < 64 * 16; i += 256) {
        int r = i >> 4, c4 = i & 15;
        float4 v = *(const float4*)&W1[(size_t)(k0 + r) * 256 + mc * 64 + c4 * 4];
        *(short4*)&a_s[r * 72 + c4 * 4] =
            make_short4((short)f2b(v.x), (short)f2b(v.y), (short)f2b(v.z), (short)f2b(v.w));
      }
      for (int i = t; i < 64 * 16; i += 256) {
        int m = i >> 4, n4 = i & 15;
        float4 v = *(const float4*)&W2[(size_t)(mc * 64 + m) * 256 + nbase + n4 * 4];
        b_s[(n4 * 4 + 0) * 72 + m] = f2b(v.x);
        b_s[(n4 * 4 + 1) * 72 + m] = f2b(v.y);
        b_s[(n4 * 4 + 2) * 72 + m] = f2b(v.z);
        b_s[(n4 * 4 + 3) * 72 + m] = f2b(v.w);
      }
      __syncthreads();
      #pragma unroll
      for (int kt = 0; kt < 2; kt++) {
        bf16x8 a = *(const bf16x8*)&a_s[(wid * 16 + lr) * 72 + kt * 32 + lg * 8];
        #pragma unroll
        for (int nt = 0; nt < 4; nt++) {
          bf16x8 bb = *(const bf16x8*)&b_s[(nt * 16 + lr) * 72 + kt * 32 + lg * 8];
          acc[nt] = __builtin_amdgcn_mfma_f32_16x16x32_bf16(a, bb, acc[nt], 0, 0, 0);
        }
      }
      __syncthreads();
    }
    #pragma unroll
    for (int nt = 0; nt < 4; nt++)
      #pragma unroll
      for (int r = 0; r < 4; r++)
        Wt12[(size_t)(nbase + nt * 16 + lr) * 256 + k0 + wid * 16 + lg * 4 + r] =
            f2b(acc[nt][r]);
  } else if (idx == 1312) {
    // ---- b12[n] = b2[n] + sum_m b1[m]*W2[m][n]; 4-way ILP chains ----
    int n = t;
    float a0 = 0.f, a1 = 0.f, a2 = 0.f, a3 = 0.f;
    #pragma unroll 4
    for (int m = 0; m < 256; m += 4) {
      a0 += b1[m + 0] * W2[(size_t)(m + 0) * 256 + n];
      a1 += b1[m + 1] * W2[(size_t)(m + 1) * 256 + n];
      a2 += b1[m + 2] * W2[(size_t)(m + 2) * 256 + n];
      a3 += b1[m + 3] * W2[(size_t)(m + 3) * 256 + n];
    }
    b12f[n] = (a0 + a1) + (a2 + a3) + b2[n];
  } else {
    // ---- gate GEMV: 256 blocks; wave: 16 px = 2 rounds x 8 in flight ----
    int w = t >> 6, lane = t & 63;
    int base = (idx - 1313) * 64 + w * 16;
    const float4 wv = *(const float4*)(gw + lane * 4);
    float gb0 = gb[0];
    #pragma unroll
    for (int rnd = 0; rnd < 2; rnd++) {
      int p0 = base + rnd * 8;
      float a0, a1, a2, a3, a4, a5, a6, a7;
      {
        float4 v0 = *(const float4*)(coarse + (size_t)(p0 + 0) * 256 + lane * 4);
        float4 v1 = *(const float4*)(coarse + (size_t)(p0 + 1) * 256 + lane * 4);
        float4 v2 = *(const float4*)(coarse + (size_t)(p0 + 2) * 256 + lane * 4);
        float4 v3 = *(const float4*)(coarse + (size_t)(p0 + 3) * 256 + lane * 4);
        float4 v4 = *(const float4*)(coarse + (size_t)(p0 + 4) * 256 + lane * 4);
        float4 v5 = *(const float4*)(coarse + (size_t)(p0 + 5) * 256 + lane * 4);
        float4 v6 = *(const float4*)(coarse + (size_t)(p0 + 6) * 256 + lane * 4);
        float4 v7 = *(const float4*)(coarse + (size_t)(p0 + 7) * 256 + lane * 4);
        a0 = v0.x * wv.x + v0.y * wv.y + v0.z * wv.z + v0.w * wv.w;
        a1 = v1.x * wv.x + v1.y * wv.y + v1.z * wv.z + v1.w * wv.w;
        a2 = v2.x * wv.x + v2.y * wv.y + v2.z * wv.z + v2.w * wv.w;
        a3 = v3.x * wv.x + v3.y * wv.y + v3.z * wv.z + v3.w * wv.w;
        a4 = v4.x * wv.x + v4.y * wv.y + v4.z * wv.z + v4.w * wv.w;
        a5 = v5.x * wv.x + v5.y * wv.y + v5.z * wv.z + v5.w * wv.w;
        a6 = v6.x * wv.x + v6.y * wv.y + v6.z * wv.z + v6.w * wv.w;
        a7 = v7.x * wv.x + v7.y * wv.y + v7.z * wv.z + v7.w * wv.w;
      }
      #pragma unroll
      for (int off2 = 32; off2; off2 >>= 1) {
        a0 += __shfl_xor(a0, off2);
        a1 += __shfl_xor(a1, off2);
        a2 += __shfl_xor(a2, off2);
        a3 += __shfl_xor(a3, off2);
        a4 += __shfl_xor(a4, off2);
        a5 += __shfl_xor(a5, off2);
        a6 += __shfl_xor(a6, off2);
        a7 += __shfl_xor(a7, off2);
      }
      if (lane == 0) {
        gatec[p0 + 0] = 1.f / (1.f + expf(-(a0 + gb0)));
        gatec[p0 + 1] = 1.f / (1.f + expf(-(a1 + gb0)));
        gatec[p0 + 2] = 1.f / (1.f + expf(-(a2 + gb0)));
        gatec[p0 + 3] = 1.f / (1.f + expf(-(a3 + gb0)));
        gatec[p0 + 4] = 1.f / (1.f + expf(-(a4 + gb0)));
        gatec[p0 + 5] = 1.f / (1.f + expf(-(a5 + gb0)));
        gatec[p0 + 6] = 1.f / (1.f + expf(-(a6 + gb0)));
        gatec[p0 + 7] = 1.f / (1.f + expf(-(a7 + gb0)));
      }
    }
  }
}

// ---------------------------------------------------------------------------
// content v2: 16x16 output tile / block; B-frags preloaded in registers.
__global__ __launch_bounds__(256) void content_both_kernel(
    const unsigned short* __restrict__ femb, const unsigned short* __restrict__ cemb,
    const unsigned short* __restrict__ Wtcnt, const float* __restrict__ cb,
    float* __restrict__ kff, float* __restrict__ kfc) {
  __shared__ __align__(16) unsigned short a_s[324 * 72];  // 46656 B (18x18 halo)
  int idx = blockIdx.x, t = threadIdx.x;
  const unsigned short* emb;
  float* out;
  int b, i0, j0, Hd, Wd;
  if (idx < 256) {
    b = idx >> 6; int rem = idx & 63;
    i0 = (rem >> 3) * 16; j0 = (rem & 7) * 16; Hd = 128; Wd = 128;
    emb = femb; out = kff;
  } else {
    int i2 = idx - 256;
    b = i2 >> 4; int rem = i2 & 15;
    i0 = (rem >> 2) * 16; j0 = (rem & 3) * 16; Hd = 64; Wd = 64;
    emb = cemb; out = kfc;
  }

  for (int i = t; i < 324 * 16; i += 256) {
    int cell = i >> 4, ck = i & 15;
    int gi = i0 - 1 + cell / 18;
    int gj = j0 - 1 + cell % 18;
    short4 v = make_short4(0, 0, 0, 0);
    if (gi >= 0 && gi < Hd && gj >= 0 && gj < Wd)
      v = *(const short4*)&emb[(size_t)((b * Hd + gi) * Wd + gj) * 64 + ck * 4];
    *(short4*)&a_s[cell * 72 + ck * 4] = v;
  }
  __syncthreads();

  int wid = t >> 6, lane = t & 63;
  int lr = lane & 15, lg = lane >> 4;
  const f32x4 zero4 = {0.f, 0.f, 0.f, 0.f};
  f32x4 acc[4][2];
  #pragma unroll
  for (int mt = 0; mt < 4; mt++)
    #pragma unroll
    for (int nt = 0; nt < 2; nt++) acc[mt][nt] = zero4;

  #pragma unroll
  for (int nt = 0; nt < 2; nt++) {
    bf16x8 wb[9][2];
    #pragma unroll
    for (int tap = 0; tap < 9; tap++)
      #pragma unroll
      for (int kt = 0; kt < 2; kt++)
        wb[tap][kt] = *(const bf16x8*)&Wtcnt[(size_t)(nt * 16 + lr) * 576 + tap * 64 + kt * 32 + lg * 8];

    #pragma unroll
    for (int mt = 0; mt < 4; mt++) {
      int m = wid * 4 + mt;
      #pragma unroll
      for (int di = 0; di < 3; di++) {
        #pragma unroll
        for (int dj = 0; dj < 3; dj++) {
          int cell = (m + di) * 18 + (lr + dj);
          int tap = di * 3 + dj;
          #pragma unroll
          for (int kt = 0; kt < 2; kt++) {
            bf16x8 a = *(const bf16x8*)&a_s[cell * 72 + kt * 32 + lg * 8];
            acc[mt][nt] = __builtin_amdgcn_mfma_f32_16x16x32_bf16(a, wb[tap][kt], acc[mt][nt], 0, 0, 0);
          }
        }
      }
    }
  }

  #pragma unroll
  for (int mt = 0; mt < 4; mt++) {
    int m = wid * 4 + mt;
    int gi = i0 + m;
    #pragma unroll
    for (int nt = 0; nt < 2; nt++) {
      int ch = nt * 16 + lr;
      if (ch < 25) {
        float bv = cb[ch];
        #pragma unroll
        for (int r = 0; r < 4; r++) {
          int gj = j0 + lg * 4 + r;
          out[(size_t)((b * Hd + gi) * Wd + gj) * 25 + ch] = acc[mt][nt][r] + bv;
        }
      }
    }
  }
}

// ---------------------------------------------------------------------------
// carafe (64 px / block): 8x8 fine tile -> 8x8 coarse window. cu_g bf16.
__global__ __launch_bounds__(256) void carafe_kernel(
    const float* __restrict__ coarse, const float* __restrict__ kff,
    const float* __restrict__ kfc, unsigned short* __restrict__ cu_g) {
  __shared__ __align__(16) unsigned short buf[256 * 72];   // win_t, then cu_s
  __shared__ __align__(16) unsigned short m_ext[64 * 72];  // 9216 B
  unsigned short* win_t = buf;
  unsigned short* cu_s  = buf;

  int t = threadIdx.x;
  int b = blockIdx.z;
  int i0 = blockIdx.y * 8, j0 = blockIdx.x * 8;
  int hw0 = (i0 >> 1) - 2, ww0 = (j0 >> 1) - 2;

  {
    #pragma unroll
    for (int p0 = 0; p0 < 64; p0 += 4) {
      unsigned short vals[4];
      #pragma unroll
      for (int q = 0; q < 4; q++) {
        int p = p0 + q;
        int h = hw0 + (p >> 3), w = ww0 + (p & 7);
        float v = 0.f;
        if (h >= 0 && h < 64 && w >= 0 && w < 64)
          v = coarse[(size_t)((b * 64 + h) * 64 + w) * 256 + t];
        vals[q] = f2b(v);
      }
      *(short4*)&win_t[t * 72 + p0] =
          make_short4((short)vals[0], (short)vals[1], (short)vals[2], (short)vals[3]);
    }
  }
  if (t < 64) {
    int ti = t >> 3, tj = t & 7;
    int i = i0 + ti, j = j0 + tj;
    size_t fpx = (size_t)((b * 128 + i) * 128 + j);
    size_t cpx = (size_t)((b * 64 + (i >> 1)) * 64 + (j >> 1));
    float v[25];
    float mx = -1e30f;
    #pragma unroll
    for (int m = 0; m < 25; m++) {
      v[m] = kff[fpx * 25 + m] + kfc[cpx * 25 + m];
      mx = fmaxf(mx, v[m]);
    }
    float s = 0.f;
    #pragma unroll
    for (int m = 0; m < 25; m++) { v[m] = expf(v[m] - mx); s += v[m]; }
    float inv = 1.f / s;
    unsigned* row32 = (unsigned*)&m_ext[t * 72];
    #pragma unroll
    for (int q = 0; q < 36; q++) row32[q] = 0;
    int wib = ti >> 1, wjb = tj >> 1;
    #pragma unroll
    for (int di = 0; di < 5; di++)
      #pragma unroll
      for (int dj = 0; dj < 5; dj++)
        m_ext[t * 72 + (wib + di) * 8 + (wjb + dj)] = f2b(v[di * 5 + dj] * inv);
  }
  __syncthreads();

  int wid = t >> 6, lane = t & 63;
  int lr = lane & 15, lg = lane >> 4;
  const f32x4 zero4 = {0.f, 0.f, 0.f, 0.f};

  f32x4 acc0[4][4];
  #pragma unroll
  for (int mi = 0; mi < 4; mi++)
    #pragma unroll
    for (int ni = 0; ni < 4; ni++) acc0[mi][ni] = zero4;
  #pragma unroll
  for (int kt = 0; kt < 2; kt++) {
    bf16x8 am[4];
    #pragma unroll
    for (int mi = 0; mi < 4; mi++)
      am[mi] = *(const bf16x8*)&m_ext[(mi * 16 + lr) * 72 + kt * 32 + lg * 8];
    #pragma unroll
    for (int ni = 0; ni < 4; ni++) {
      bf16x8 bb = *(const bf16x8*)&win_t[(size_t)(wid * 64 + ni * 16 + lr) * 72 + kt * 32 + lg * 8];
      #pragma unroll
      for (int mi = 0; mi < 4; mi++)
        acc0[mi][ni] = __builtin_amdgcn_mfma_f32_16x16x32_bf16(am[mi], bb, acc0[mi][ni], 0, 0, 0);
    }
  }
  __syncthreads();

  #pragma unroll
  for (int mi = 0; mi < 4; mi++)
    #pragma unroll
    for (int ni = 0; ni < 4; ni++)
      #pragma unroll
      for (int r = 0; r < 4; r++)
        cu_s[(mi * 16 + lg * 4 + r) * 264 + wid * 64 + ni * 16 + lr] = f2b(acc0[mi][ni][r]);
  __syncthreads();

  for (int c = t; c < 2048; c += 256) {
    int p = c >> 5, off = (c & 31) << 3;
    int gi = i0 + (p >> 3), gj = j0 + (p & 7);
    bf16x8 v = *(const bf16x8*)&cu_s[p * 264 + off];
    *(bf16x8*)&cu_g[(size_t)((b * 128 + gi) * 128 + gj) * 256 + off] = v;
  }
}

// ---------------------------------------------------------------------------
// proj: persistent 4-tile pipeline, weights in regs, LDS double buffer.
__global__ __launch_bounds__(256, 2) void proj_kernel(
    const unsigned short* __restrict__ cu_g, const float* __restrict__ gatec,
    const unsigned short* __restrict__ Wt1, const float* __restrict__ b1,
    const unsigned short* __restrict__ Wt12, const float* __restrict__ b12,
    float* __restrict__ out) {
  __shared__ __align__(16) unsigned short a_s[2][64 * 264];
  __shared__ float g_s[2][32];
  int t = threadIdx.x;
  int bid = blockIdx.x;
  int cg = bid >> 8;
  int g  = bid & 255;
  int wid = t >> 6, lane = t & 63;
  int lr = lane & 15, lg = lane >> 4;
  int n0 = cg * 64 + wid * 16;

  bf16x8 wb1[8], wb12[8];
  #pragma unroll
  for (int kt = 0; kt < 8; kt++) {
    size_t wrow = (size_t)(n0 + lr) * 256 + kt * 32 + lg * 8;
    wb1[kt]  = *(const bf16x8*)&Wt1[wrow];
    wb12[kt] = *(const bf16x8*)&Wt12[wrow];
  }
  float b1v  = b1[n0 + lr];
  float b12v = b12[n0 + lr];

  {
    size_t m0 = (size_t)g * 256;
    for (int c = t; c < 2048; c += 256) {
      int row = c >> 5, off = (c & 31) << 3;
      *(bf16x8*)&a_s[0][row * 264 + off] = *(const bf16x8*)&cu_g[(m0 + row) * 256 + off];
    }
    if (t < 32) {
      int b_ = (int)(m0 >> 14), ii = (int)((m0 >> 7) & 127), j0 = (int)(m0 & 127);
      g_s[0][t] = gatec[(size_t)(b_ * 64 + (ii >> 1)) * 64 + (j0 >> 1) + t];
    }
  }
  __syncthreads();

  const f32x4 zero4 = {0.f, 0.f, 0.f, 0.f};

  for (int it = 0; it < 4; ++it) {
    int cur = it & 1, nxt = cur ^ 1;
    size_t m0i = (size_t)(g * 4 + it) * 64;

    bf16x8 pf[8];
    float gpf = 0.f;
    if (it < 3) {
      size_t m0n = m0i + 64;
      #pragma unroll
      for (int q = 0; q < 8; q++) {
        int c = t + q * 256;
        int row = c >> 5, off = (c & 31) << 3;
        pf[q] = *(const bf16x8*)&cu_g[(m0n + row) * 256 + off];
      }
      if (t < 32) {
        int b_ = (int)(m0n >> 14), ii = (int)((m0n >> 7) & 127), j0 = (int)(m0n & 127);
        gpf = gatec[(size_t)(b_ * 64 + (ii >> 1)) * 64 + (j0 >> 1) + t];
      }
    }

    f32x4 accc[4] = {zero4, zero4, zero4, zero4};
    f32x4 accf[4] = {zero4, zero4, zero4, zero4};
    #pragma unroll
    for (int kt = 0; kt < 8; kt++) {
      #pragma unroll
      for (int mi = 0; mi < 4; mi++) {
        bf16x8 a = *(const bf16x8*)&a_s[cur][(mi * 16 + lr) * 264 + kt * 32 + lg * 8];
        accc[mi] = __builtin_amdgcn_mfma_f32_16x16x32_bf16(a, wb1[kt],  accc[mi], 0, 0, 0);
        accf[mi] = __builtin_amdgcn_mfma_f32_16x16x32_bf16(a, wb12[kt], accf[mi], 0, 0, 0);
      }
    }

    if (it < 3) {
      #pragma unroll
      for (int q = 0; q < 8; q++) {
        int c = t + q * 256;
        int row = c >> 5, off = (c & 31) << 3;
        *(bf16x8*)&a_s[nxt][row * 264 + off] = pf[q];
      }
      if (t < 32) g_s[nxt][t] = gpf;
    }

    #pragma unroll
    for (int mi = 0; mi < 4; mi++) {
      #pragma unroll
      for (int r = 0; r < 4; r++) {
        int row = mi * 16 + lg * 4 + r;
        float gg = g_s[cur][row >> 1];
        float f_out = accf[mi][r] + b12v;
        float c_out = accc[mi][r] + b1v;
        out[(m0i + row) * 256 + n0 + lr] = gg * f_out + (1.f - gg) * c_out;
      }
    }

    if (it < 3) __syncthreads();
  }
}

// ---------------------------------------------------------------------------
extern "C" void kernel_launch(void* const* d_in, const int* in_sizes, int n_in,
                              void* d_out, int out_size, void* d_ws, size_t ws_size,
                              hipStream_t stream) {
  const float* fine        = (const float*)d_in[0];
  const float* coarse      = (const float*)d_in[1];
  const float* gate_w      = (const float*)d_in[2];
  const float* gate_b      = (const float*)d_in[3];
  const float* ss_fine_w   = (const float*)d_in[4];
  const float* ss_fine_b   = (const float*)d_in[5];
  const float* ss_coarse_w = (const float*)d_in[6];
  const float* ss_content_w= (const float*)d_in[7];
  const float* ss_content_b= (const float*)d_in[8];
  const float* W1          = (const float*)d_in[9];
  const float* b1          = (const float*)d_in[10];
  const float* W2          = (const float*)d_in[11];
  const float* b2          = (const float*)d_in[12];
  float* out = (float*)d_out;

  char* ws = (char*)d_ws;
  size_t off = 0;
  float* gatec = (float*)(ws + off); off += 131072;
  unsigned short* femb = (unsigned short*)(ws + off); off += (size_t)Nf * 64 * 2;
  unsigned short* cemb = (unsigned short*)(ws + off); off += (size_t)Nc * 64 * 2;
  float* kff   = (float*)(ws + off); off += (size_t)Nf * 25 * 4;
  float* kfc   = (float*)(ws + off); off += (size_t)Nc * 25 * 4;
  unsigned short* Wt1 = (unsigned short*)(ws + off); off += 65536 * 2;
  unsigned short* Wtf = (unsigned short*)(ws + off); off += 64 * 128 * 2;
  unsigned short* Wtc = (unsigned short*)(ws + off); off += 64 * 256 * 2;
  unsigned short* Wtcnt = (unsigned short*)(ws + off); off += 32 * 576 * 2;
  unsigned short* Wt12 = (unsigned short*)(ws + off); off += 65536 * 2;
  float* b12f = (float*)(ws + off); off += 1024;
  unsigned short* cu_g = (unsigned short*)(ws + off); off += (size_t)Nf * 256 * 2;

  prepA_kernel<<<168, 256, 0, stream>>>(ss_fine_w, ss_coarse_w, ss_content_w,
                                        Wtf, Wtc, Wtcnt);
  emb_prepB_kernel<<<1569, 256, 0, stream>>>(
      fine, Wtf, ss_fine_b, femb, coarse, Wtc, cemb,
      W1, W2, Wt1, Wt12, b12f, b1, b2, gate_w, gate_b, gatec);
  content_both_kernel<<<256 + 64, 256, 0, stream>>>(
      femb, cemb, Wtcnt, ss_content_b, kff, kfc);
  carafe_kernel<<<dim3(Wf / 8, Hf / 8, Bb), 256, 0, stream>>>(coarse, kff, kfc, cu_g);
  proj_kernel<<<1024, 256, 0, stream>>>(cu_g, gatec, Wt1, b1, Wt12, b12f, out);
}